// Round 35
// baseline (253.329 us; speedup 1.0000x reference)
//
#include <hip/hip_runtime.h>

typedef short short8 __attribute__((ext_vector_type(8)));
typedef float f32x4 __attribute__((ext_vector_type(4)));
typedef unsigned short u16;

#define NTOK 16281
#define NPAD 16384
#define NPATH 281
#define HEADS 8
#define CHUNK 2036          // key-split for path queries (8 chunks)
#define KVB 128             // KV tile per inner iteration
#define PATH_QT 5           // ceil(281/64)
#define PATH_BLOCKS2 (HEADS * PATH_QT * 8)             // 320
#define HIST_QT2 250        // 16000/64
#define ATTN_BLOCKS2 (PATH_BLOCKS2 + HEADS * HIST_QT2) // 2320
#define NPADROWS (NPAD - NTOK)   // 103
#define ZERON (HEADS * NPADROWS * 64)  // 52736

static __device__ __forceinline__ u16 f2bf(float f) {
  unsigned u = __float_as_uint(f);
  u += 0x7FFFu + ((u >> 16) & 1u);
  return (u16)(u >> 16);
}
static __device__ __forceinline__ float bf2f(u16 h) {
  return __uint_as_float(((unsigned)h) << 16);
}
static __device__ __forceinline__ uint2 pack4(float4 v) {
  uint2 o;
  o.x = (unsigned)f2bf(v.x) | ((unsigned)f2bf(v.y) << 16);
  o.y = (unsigned)f2bf(v.z) | ((unsigned)f2bf(v.w) << 16);
  return o;
}

// ---- K0: zero the padded rows (16281..16383) of Qb/Kb/Vb every call --------
// Makes workspace state deterministic (r13 tripwire fix) without touching the
// proven GEMM binary.
__global__ __launch_bounds__(256) void k_zeropad(u16* __restrict__ Qb,
                                                 u16* __restrict__ Kb,
                                                 u16* __restrict__ Vb) {
  int i = blockIdx.x * 256 + threadIdx.x;
  if (i >= ZERON) return;
  int d = i & 63;
  int rr = (i >> 6) % NPADROWS;
  int h = i / (NPADROWS * 64);
  size_t off = ((size_t)h * NPAD + NTOK + rr) * 64 + d;
  Qb[off] = 0; Kb[off] = 0; Vb[off] = 0;
}

// ---- K1: QKV GEMM (bf16 MFMA) — byte-identical to the r11/r12/r13 binary ---
__global__ __launch_bounds__(256) void k_gemm_qkv(const float* __restrict__ x,
                                                  const float* __restrict__ w,
                                                  u16* __restrict__ Qb,
                                                  u16* __restrict__ Kb,
                                                  u16* __restrict__ Vb) {
  __shared__ u16 As[128 * 32];
  __shared__ u16 Bs[128 * 32];
  const int bm = blockIdx.x, bn = blockIdx.y;
  const int t = threadIdx.x;
  const int lane = t & 63, wv = t >> 6;
  const int wr = wv >> 1, wc = wv & 1;
  const int lr = lane & 15, kq = lane >> 4;
  f32x4 acc[4][4] = {};
  for (int ks = 0; ks < 512; ks += 32) {
    for (int c = t; c < 1024; c += 256) {
      int row = c >> 3, c4 = (c & 7) << 2;
      int gr = bm * 128 + row;
      float4 va = {0.f, 0.f, 0.f, 0.f};
      if (gr < NTOK)
        va = *reinterpret_cast<const float4*>(&x[(size_t)gr * 512 + ks + c4]);
      *reinterpret_cast<uint2*>(&As[row * 32 + c4]) = pack4(va);
      float4 vb = *reinterpret_cast<const float4*>(&w[(size_t)(bn * 128 + row) * 512 + ks + c4]);
      *reinterpret_cast<uint2*>(&Bs[row * 32 + c4]) = pack4(vb);
    }
    __syncthreads();
    short8 af[4], bfr[4];
#pragma unroll
    for (int i = 0; i < 4; i++) {
      af[i]  = *reinterpret_cast<const short8*>(&As[(wr * 64 + i * 16 + lr) * 32 + kq * 8]);
      bfr[i] = *reinterpret_cast<const short8*>(&Bs[(wc * 64 + i * 16 + lr) * 32 + kq * 8]);
    }
#pragma unroll
    for (int i = 0; i < 4; i++)
#pragma unroll
      for (int j = 0; j < 4; j++)
        acc[i][j] = __builtin_amdgcn_mfma_f32_16x16x32_bf16(af[i], bfr[j], acc[i][j], 0, 0, 0);
    __syncthreads();
  }
#pragma unroll
  for (int i = 0; i < 4; i++) {
#pragma unroll
    for (int j = 0; j < 4; j++) {
#pragma unroll
      for (int r = 0; r < 4; r++) {
        int row = wr * 64 + i * 16 + kq * 4 + r;
        int col = wc * 64 + j * 16 + lr;
        int n = bm * 128 + row;
        if (n < NTOK) {
          int e = bn * 128 + col;
          int which = e >> 9, h = (e >> 6) & 7, d = e & 63;
          float v = acc[i][j][r];
          size_t off = ((size_t)h * NPAD + n) * 64 + d;
          if (which == 0)      Qb[off] = f2bf(v * 0.125f);
          else if (which == 1) Kb[off] = f2bf(v);
          else                 Vb[off] = f2bf(v);
        }
      }
    }
  }
}

// ---- K2: V transpose Vb[h][key][d] -> VbT[h][d][key] -----------------------
__global__ __launch_bounds__(256) void k_vt(const u16* __restrict__ Vb,
                                            u16* __restrict__ VbT) {
  __shared__ u16 T[128 * 64];
  const int h = blockIdx.x, kt = blockIdx.y;
  const int t = threadIdx.x;
#pragma unroll
  for (int it = 0; it < 4; it++) {
    int i = t + it * 256;
    int row = i >> 3, dc = i & 7;
    uint4 vv = *reinterpret_cast<const uint4*>(
        &Vb[((size_t)h * NPAD + kt * 128 + row) * 64 + dc * 8]);
    *reinterpret_cast<uint4*>(&T[row * 64 + ((dc ^ (row & 7)) << 3)]) = vv;
  }
  __syncthreads();
  const int d = t & 63, wv = t >> 6;
#pragma unroll
  for (int it = 0; it < 4; it++) {
    int kc = wv + it * 4;
    u16 g[8];
#pragma unroll
    for (int u = 0; u < 8; u++) {
      int key = kc * 8 + u;
      g[u] = T[key * 64 + ((((d >> 3) ^ (key & 7)) << 3) | (d & 7))];
    }
    *reinterpret_cast<uint4*>(&VbT[((size_t)h * 64 + d) * NPAD + kt * 128 + kc * 8]) =
        *reinterpret_cast<uint4*>(g);
  }
}

// ---- K3: MFMA flash attention (V via direct-global VbT B-frags) ------------
__global__ __launch_bounds__(256) void k_attn_mfma(const u16* __restrict__ Qb,
                                                   const u16* __restrict__ Kb,
                                                   const u16* __restrict__ VbT,
                                                   float* __restrict__ dout,
                                                   float* __restrict__ pp) {
  __shared__ u16 Kt[KVB * 64];      // 16 KB [key][d], swizzled
  __shared__ u16 Pt[4][16 * KVB];   // 16 KB per-wave P, swizzled

  const int b = blockIdx.x, t = threadIdx.x;
  const int lane = t & 63, wq = t >> 6;
  const int c = lane & 15, g = lane >> 4;
  int h, q0, k0, k1, qlim;
  bool path;
  if (b < PATH_BLOCKS2) {
    path = true;
    int qt = (b >> 3) % PATH_QT;
    h = b / (8 * PATH_QT);
    q0 = qt * 64;
    k0 = (b & 7) * CHUNK;
    k1 = min(k0 + CHUNK, NTOK);
    qlim = NPATH;
  } else {
    path = false;
    int bb = b - PATH_BLOCKS2;
    h = bb / HIST_QT2;
    q0 = NPATH + (bb % HIST_QT2) * 64;
    k0 = 0; k1 = NPATH;
    qlim = NTOK;
  }
  const int q = q0 + wq * 16 + c;
  short8 qf0 = {}, qf1 = {};
  if (q < qlim) {
    qf0 = *reinterpret_cast<const short8*>(&Qb[((size_t)h * NPAD + q) * 64 + g * 8]);
    qf1 = *reinterpret_cast<const short8*>(&Qb[((size_t)h * NPAD + q) * 64 + 32 + g * 8]);
  }
  const u16* vt = VbT + (size_t)h * 64 * NPAD;
  float m_run[4], l_run[4];
#pragma unroll
  for (int r = 0; r < 4; r++) { m_run[r] = -1e30f; l_run[r] = 0.f; }
  f32x4 o[4] = {};

  for (int j0 = k0; j0 < k1; j0 += KVB) {
    const int jn = min(KVB, k1 - j0);
    __syncthreads();
#pragma unroll
    for (int it = 0; it < 4; it++) {
      int i = t + it * 256;
      int row = i >> 3, cc = i & 7;
      uint4 vv = {0u, 0u, 0u, 0u};
      if (row < jn)
        vv = *reinterpret_cast<const uint4*>(&Kb[((size_t)h * NPAD + j0 + row) * 64 + cc * 8]);
      *reinterpret_cast<uint4*>(&Kt[row * 64 + ((cc ^ (row & 7)) << 3)]) = vv;
    }
    __syncthreads();
    f32x4 s[8];
#pragma unroll
    for (int kt = 0; kt < 8; kt++) {
      int key = kt * 16 + c;
      int swz = (key & 7) << 3;
      short8 bk0 = *reinterpret_cast<const short8*>(&Kt[key * 64 + ((g * 8) ^ swz)]);
      short8 bk1 = *reinterpret_cast<const short8*>(&Kt[key * 64 + ((32 + g * 8) ^ swz)]);
      f32x4 z = {0.f, 0.f, 0.f, 0.f};
      z = __builtin_amdgcn_mfma_f32_16x16x32_bf16(qf0, bk0, z, 0, 0, 0);
      s[kt] = __builtin_amdgcn_mfma_f32_16x16x32_bf16(qf1, bk1, z, 0, 0, 0);
    }
    if (jn < KVB) {
#pragma unroll
      for (int kt = 0; kt < 8; kt++)
        if (kt * 16 + c >= jn) {
          s[kt][0] = -1e30f; s[kt][1] = -1e30f; s[kt][2] = -1e30f; s[kt][3] = -1e30f;
        }
    }
    float fac[4];
#pragma unroll
    for (int r = 0; r < 4; r++) {
      float m2 = s[0][r];
#pragma unroll
      for (int kt = 1; kt < 8; kt++) m2 = fmaxf(m2, s[kt][r]);
#pragma unroll
      for (int msk = 1; msk < 16; msk <<= 1) m2 = fmaxf(m2, __shfl_xor(m2, msk, 64));
      float mnew = fmaxf(m_run[r], m2);
      fac[r] = __expf(m_run[r] - mnew);
      m_run[r] = mnew;
    }
#pragma unroll
    for (int r = 0; r < 4; r++) {
      float ps = 0.f;
#pragma unroll
      for (int kt = 0; kt < 8; kt++) {
        float e = __expf(s[kt][r] - m_run[r]);
        s[kt][r] = e;
        ps += e;
      }
#pragma unroll
      for (int msk = 1; msk < 16; msk <<= 1) ps += __shfl_xor(ps, msk, 64);
      l_run[r] = l_run[r] * fac[r] + ps;
    }
#pragma unroll
    for (int dt = 0; dt < 4; dt++) {
#pragma unroll
      for (int r = 0; r < 4; r++) o[dt][r] *= fac[r];
    }
#pragma unroll
    for (int r = 0; r < 4; r++) {
      int qrow = g * 4 + r;
      int swz = (qrow & 7) << 3;
#pragma unroll
      for (int kt = 0; kt < 8; kt++)
        Pt[wq][qrow * KVB + ((kt * 16 + c) ^ swz)] = f2bf(s[kt][r]);
    }
#pragma unroll
    for (int ks = 0; ks < 4; ks++) {
      short8 pa = *reinterpret_cast<const short8*>(
          &Pt[wq][c * KVB + ((ks * 32 + g * 8) ^ ((c & 7) << 3))]);
#pragma unroll
      for (int dt = 0; dt < 4; dt++) {
        short8 bv = *reinterpret_cast<const short8*>(
            &vt[(size_t)(dt * 16 + c) * NPAD + j0 + ks * 32 + g * 8]);
        o[dt] = __builtin_amdgcn_mfma_f32_16x16x32_bf16(pa, bv, o[dt], 0, 0, 0);
      }
    }
  }

  if (path) {
    int kc = b & 7;
#pragma unroll
    for (int r = 0; r < 4; r++) {
      int qp = q0 + wq * 16 + g * 4 + r;
      if (qp < NPATH) {
        float* base = pp + ((size_t)(h * 8 + kc) * NPATH + qp) * 66;
#pragma unroll
        for (int dt = 0; dt < 4; dt++) base[dt * 16 + c] = o[dt][r];
        if (c == 0) { base[64] = m_run[r]; base[65] = l_run[r]; }
      }
    }
  } else {
#pragma unroll
    for (int r = 0; r < 4; r++) {
      int qn = q0 + wq * 16 + g * 4 + r;
      float inv = 1.f / l_run[r];
#pragma unroll
      for (int dt = 0; dt < 4; dt++)
        dout[(size_t)qn * 512 + h * 64 + dt * 16 + c] += o[dt][r] * inv;
    }
  }
}

// ---- K4: combine path partials over 8 key chunks (adds into conv base) -----
__global__ void k_combine(const float* __restrict__ pp, float* __restrict__ dout) {
  const int b = blockIdx.x;       // 8*281
  const int h = b / NPATH, q = b % NPATH;
  const int d = threadIdx.x;      // 64
  const float* base0 = pp + ((size_t)(h * 8) * NPATH + q) * 66;
  const size_t cs = (size_t)NPATH * 66;
  float m = -1e30f;
  for (int c = 0; c < 8; c++) m = fmaxf(m, base0[c * cs + 64]);
  float l = 0.f, o = 0.f;
  for (int c = 0; c < 8; c++) {
    const float* base = base0 + c * cs;
    float sc = __expf(base[64] - m);
    l += sc * base[65];
    o += sc * base[d];
  }
  dout[(size_t)q * 512 + h * 64 + d] += o / l;
}

// ---- K5: depthwise conv (kernel 33) over V — runs FIRST, writes "=" --------
__global__ __launch_bounds__(256) void k_conv(const u16* __restrict__ Vb,
                                              const float* __restrict__ wres,
                                              float* __restrict__ dout) {
  __shared__ float Vs[96][64];
  __shared__ float wr[33];
  const int b = blockIdx.x;          // 8 * 255
  const int h = b / 255, n0 = (b % 255) * 64;
  const int t = threadIdx.x;
  if (t < 33) wr[t] = wres[h * 33 + t];
  for (int i = t; i < 96 * 64; i += 256) {
    int rr = i >> 6, dd = i & 63;
    int n = n0 - 16 + rr;
    Vs[rr][dd] = (n >= 0 && n < NTOK) ? bf2f(Vb[((size_t)h * NPAD + n) * 64 + dd]) : 0.f;
  }
  __syncthreads();
  const int d = t & 63, ns = t >> 6;
  for (int i = 0; i < 16; i++) {
    int nn = ns * 16 + i;
    int n = n0 + nn;
    if (n < NTOK) {
      float s = 0.f;
#pragma unroll
      for (int u = 0; u < 33; u++) s += Vs[nn + u][d] * wr[u];
      dout[(size_t)n * 512 + h * 64 + d] = s;   // "=" : conv is the base term
    }
  }
}

extern "C" void kernel_launch(void* const* d_in, const int* in_sizes, int n_in,
                              void* d_out, int out_size, void* d_ws, size_t ws_size,
                              hipStream_t stream) {
  const float* x    = (const float*)d_in[0];
  const float* wqkv = (const float*)d_in[1];
  const float* wres = (const float*)d_in[2];
  float* out = (float*)d_out;
  char* ws = (char*)d_ws;
  // ws: Qb 0 | Kb 16.78M | Vb 33.55M (later aliased by pp) | VbT 50.33M ; NEED 67.1MB
  const size_t NEED = 67108864;
  if (ws_size < NEED) return;
  u16*   Qb  = (u16*)(ws + 0);
  u16*   Kb  = (u16*)(ws + 16777216);
  u16*   Vb  = (u16*)(ws + 33554432);
  u16*   VbT = (u16*)(ws + 50331648);
  float* pp  = (float*)(ws + 33554432);   // aliases Vb (dead after k_vt)

  hipLaunchKernelGGL(k_zeropad, dim3((ZERON + 255) / 256), dim3(256), 0, stream, Qb, Kb, Vb);
  hipLaunchKernelGGL(k_gemm_qkv, dim3(128, 12), dim3(256), 0, stream, x, wqkv, Qb, Kb, Vb);
  hipLaunchKernelGGL(k_conv, dim3(HEADS * 255), dim3(256), 0, stream, Vb, wres, out);
  hipLaunchKernelGGL(k_vt, dim3(HEADS, 128), dim3(256), 0, stream, Vb, VbT);
  hipLaunchKernelGGL(k_attn_mfma, dim3(ATTN_BLOCKS2), dim3(256), 0, stream, Qb, Kb, VbT, out, pp);
  hipLaunchKernelGGL(k_combine, dim3(HEADS * NPATH), dim3(64), 0, stream, pp, out);
}